// Round 14
// baseline (259.119 us; speedup 1.0000x reference)
//
#include <hip/hip_runtime.h>

#define BIG_NEG_F (-4294967296.0f)

typedef __attribute__((ext_vector_type(8))) short bf16x8;
typedef __attribute__((ext_vector_type(4))) float f32x4;

__device__ __forceinline__ float wave_sum(float v) {
#pragma unroll
    for (int m = 32; m; m >>= 1) v += __shfl_xor(v, m, 64);
    return v;
}
__device__ __forceinline__ float wave_max(float v) {
#pragma unroll
    for (int m = 32; m; m >>= 1) v = fmaxf(v, __shfl_xor(v, m, 64));
    return v;
}

__device__ __forceinline__ unsigned int pack2(float a, float b) {
    return (__float_as_uint(b) & 0xffff0000u) | (__float_as_uint(a) >> 16);
}
__device__ __forceinline__ float hipart(float x) {
    return __uint_as_float(__float_as_uint(x) & 0xffff0000u);
}
// split two float4 into hi/lo bf16 (truncation split: hi exact-representable, lo = residual)
__device__ __forceinline__ void store_pair(unsigned short* hp, unsigned short* lp,
                                           float4 a, float4 b) {
    uint4 h;
    h.x = pack2(a.x, a.y); h.y = pack2(a.z, a.w);
    h.z = pack2(b.x, b.y); h.w = pack2(b.z, b.w);
    float lax = a.x - hipart(a.x), lay = a.y - hipart(a.y);
    float laz = a.z - hipart(a.z), law = a.w - hipart(a.w);
    float lbx = b.x - hipart(b.x), lby = b.y - hipart(b.y);
    float lbz = b.z - hipart(b.z), lbw = b.w - hipart(b.w);
    uint4 l;
    l.x = pack2(lax, lay); l.y = pack2(laz, law);
    l.z = pack2(lbx, lby); l.w = pack2(lbz, lbw);
    *(uint4*)hp = h;
    *(uint4*)lp = l;
}

// Fused: detect mask layout (u8/i32/i64) from first 2048 bytes, normalize this row's bit,
// x = seq*keep, q = ln1(x). One block per row.
__global__ __launch_bounds__(256) void prep_ln_kernel(const float* __restrict__ seq,
                                                      const unsigned char* __restrict__ mraw,
                                                      unsigned char* __restrict__ mout,
                                                      float* __restrict__ X, float* __restrict__ Q,
                                                      const float* __restrict__ g,
                                                      const float* __restrict__ be) {
    __shared__ int flags[2];
    __shared__ float ws[8];
    int row = blockIdx.x, tid = threadIdx.x;
    if (tid == 0) { flags[0] = 0; flags[1] = 0; }
    __syncthreads();
    for (int i = tid; i < 2048; i += 256) {
        if (mraw[i]) {
            if (i & 3) atomicOr(&flags[0], 1);
            else if (i & 4) atomicOr(&flags[1], 1);
        }
    }
    __syncthreads();
    int mode = flags[0] ? 0 : (flags[1] ? 1 : 2);  // 0=u8, 1=i32, 2=i64
    unsigned char mrow = (mode == 0) ? mraw[row] : (mode == 1) ? mraw[row * 4] : mraw[row * 8];
    if (tid == 0) mout[row] = mrow ? 1 : 0;
    int idx = row * 256 + tid;
    int w = tid >> 6, lane = tid & 63;
    float v = mrow ? 0.f : seq[idx];
    X[idx] = v;
    float s = wave_sum(v);
    if (lane == 0) ws[w] = s;
    __syncthreads();
    float mean = (ws[0] + ws[1] + ws[2] + ws[3]) * (1.f / 256.f);
    float d = v - mean;
    float s2 = wave_sum(d * d);
    if (lane == 0) ws[4 + w] = s2;
    __syncthreads();
    float var = (ws[4] + ws[5] + ws[6] + ws[7]) * (1.f / 256.f);
    Q[idx] = d / sqrtf(var + 1e-8f) * g[tid] + be[tid];
}

// row layernorm over H=256, one block per row; shfl reductions (2 barriers)
__global__ __launch_bounds__(256) void ln_kernel(const float* __restrict__ X, float* __restrict__ Y,
                                                 const float* __restrict__ g,
                                                 const float* __restrict__ be) {
    __shared__ float ws[8];
    int row = blockIdx.x, tid = threadIdx.x;
    int idx = row * 256 + tid;
    int w = tid >> 6, lane = tid & 63;
    float v = X[idx];
    float s = wave_sum(v);
    if (lane == 0) ws[w] = s;
    __syncthreads();
    float mean = (ws[0] + ws[1] + ws[2] + ws[3]) * (1.f / 256.f);
    float d = v - mean;
    float s2 = wave_sum(d * d);
    if (lane == 0) ws[4 + w] = s2;
    __syncthreads();
    float var = (ws[4] + ws[5] + ws[6] + ws[7]) * (1.f / 256.f);
    Y[idx] = d / sqrtf(var + 1e-8f) * g[tid] + be[tid];
}

struct GemmJob {
    const float* A;            // [2048,256]
    const float* W;            // [256,256] row-major (out,in)
    const float* bias;         // [256]
    const float* pos;          // [256,256] per-position add, or null
    const float* res;          // residual add, or null
    const unsigned char* maskm;// row mask (zero out), or null
    float* C;                  // [2048,256]
    int relu;
};

// MFMA GEMM (r11 structure — best measured): C = A·W^T via split-precision bf16
// (A·B ≈ Ah·Bh + Ah·Bl + Al·Bh, rel err ~2^-16). 64x64 tile, BK=64, 4 waves as 2x2.
// r12/r13 lesson: direct-fragment loads are transaction-bound and pre-splitting buys
// nothing — in-kernel split during staging is NOT the limiter. Fragment layouts
// HW-verified r11. LDS rows padded to 72 ushorts. Register-prefetch of next K-tile.
__global__ __launch_bounds__(256) void gemm_mfma_kernel(GemmJob j0, GemmJob j1, GemmJob j2) {
    GemmJob J = (blockIdx.z == 0) ? j0 : (blockIdx.z == 1 ? j1 : j2);
    __shared__ unsigned short Ah[64][72], Al[64][72], Wh[64][72], Wl[64][72];
    int tid = threadIdx.x;
    int n0 = blockIdx.x * 64, m0 = blockIdx.y * 64;
    int w = tid >> 6, lane = tid & 63;
    int wm = w >> 1, wn = w & 1;
    int srow = tid >> 2, sq = tid & 3;          // staging: row 0..63, k-quarter 0..3
    const float* Asrc = J.A + (m0 + srow) * 256 + sq * 16;
    const float* Wsrc = J.W + (n0 + srow) * 256 + sq * 16;
    float4 ar0 = *(const float4*)(Asrc),      ar1 = *(const float4*)(Asrc + 4),
           ar2 = *(const float4*)(Asrc + 8),  ar3 = *(const float4*)(Asrc + 12);
    float4 wr0 = *(const float4*)(Wsrc),      wr1 = *(const float4*)(Wsrc + 4),
           wr2 = *(const float4*)(Wsrc + 8),  wr3 = *(const float4*)(Wsrc + 12);
    f32x4 acc[2][2] = {};
    int r15 = lane & 15, hgrp = (lane >> 4) << 3;
    for (int kt = 0; kt < 4; ++kt) {
        if (kt) __syncthreads();                // previous compute done before overwrite
        store_pair(&Ah[srow][sq * 16],     &Al[srow][sq * 16],     ar0, ar1);
        store_pair(&Ah[srow][sq * 16 + 8], &Al[srow][sq * 16 + 8], ar2, ar3);
        store_pair(&Wh[srow][sq * 16],     &Wl[srow][sq * 16],     wr0, wr1);
        store_pair(&Wh[srow][sq * 16 + 8], &Wl[srow][sq * 16 + 8], wr2, wr3);
        __syncthreads();
        if (kt < 3) {                           // prefetch next K-tile; retires under MFMAs
            int ko = (kt + 1) * 64;
            ar0 = *(const float4*)(Asrc + ko);      ar1 = *(const float4*)(Asrc + ko + 4);
            ar2 = *(const float4*)(Asrc + ko + 8);  ar3 = *(const float4*)(Asrc + ko + 12);
            wr0 = *(const float4*)(Wsrc + ko);      wr1 = *(const float4*)(Wsrc + ko + 4);
            wr2 = *(const float4*)(Wsrc + ko + 8);  wr3 = *(const float4*)(Wsrc + ko + 12);
        }
#pragma unroll
        for (int s = 0; s < 2; ++s) {
            int ko = s * 32 + hgrp;
            bf16x8 ah0 = *(const bf16x8*)&Ah[wm * 32 + r15][ko];
            bf16x8 ah1 = *(const bf16x8*)&Ah[wm * 32 + 16 + r15][ko];
            bf16x8 al0 = *(const bf16x8*)&Al[wm * 32 + r15][ko];
            bf16x8 al1 = *(const bf16x8*)&Al[wm * 32 + 16 + r15][ko];
            bf16x8 bh0 = *(const bf16x8*)&Wh[wn * 32 + r15][ko];
            bf16x8 bh1 = *(const bf16x8*)&Wh[wn * 32 + 16 + r15][ko];
            bf16x8 bl0 = *(const bf16x8*)&Wl[wn * 32 + r15][ko];
            bf16x8 bl1 = *(const bf16x8*)&Wl[wn * 32 + 16 + r15][ko];
            acc[0][0] = __builtin_amdgcn_mfma_f32_16x16x32_bf16(ah0, bh0, acc[0][0], 0, 0, 0);
            acc[0][0] = __builtin_amdgcn_mfma_f32_16x16x32_bf16(ah0, bl0, acc[0][0], 0, 0, 0);
            acc[0][0] = __builtin_amdgcn_mfma_f32_16x16x32_bf16(al0, bh0, acc[0][0], 0, 0, 0);
            acc[0][1] = __builtin_amdgcn_mfma_f32_16x16x32_bf16(ah0, bh1, acc[0][1], 0, 0, 0);
            acc[0][1] = __builtin_amdgcn_mfma_f32_16x16x32_bf16(ah0, bl1, acc[0][1], 0, 0, 0);
            acc[0][1] = __builtin_amdgcn_mfma_f32_16x16x32_bf16(al0, bh1, acc[0][1], 0, 0, 0);
            acc[1][0] = __builtin_amdgcn_mfma_f32_16x16x32_bf16(ah1, bh0, acc[1][0], 0, 0, 0);
            acc[1][0] = __builtin_amdgcn_mfma_f32_16x16x32_bf16(ah1, bl0, acc[1][0], 0, 0, 0);
            acc[1][0] = __builtin_amdgcn_mfma_f32_16x16x32_bf16(al1, bh0, acc[1][0], 0, 0, 0);
            acc[1][1] = __builtin_amdgcn_mfma_f32_16x16x32_bf16(ah1, bh1, acc[1][1], 0, 0, 0);
            acc[1][1] = __builtin_amdgcn_mfma_f32_16x16x32_bf16(ah1, bl1, acc[1][1], 0, 0, 0);
            acc[1][1] = __builtin_amdgcn_mfma_f32_16x16x32_bf16(al1, bh1, acc[1][1], 0, 0, 0);
        }
    }
    // epilogue: C/D layout col=lane&15, row=(lane>>4)*4+rr
#pragma unroll
    for (int mf = 0; mf < 2; ++mf) {
#pragma unroll
        for (int nf = 0; nf < 2; ++nf) {
            int col = n0 + wn * 32 + nf * 16 + r15;
            int rowb = m0 + wm * 32 + mf * 16 + ((lane >> 4) << 2);
            float bcol = J.bias[col];
            f32x4 a = acc[mf][nf];
#pragma unroll
            for (int rr = 0; rr < 4; ++rr) {
                int m = rowb + rr;
                float v = a[rr] + bcol;
                if (J.pos) v += J.pos[(m & 255) * 256 + col];
                if (J.relu) v = fmaxf(v, 0.f);
                if (J.res) v += J.res[m * 256 + col];
                if (J.maskm && J.maskm[m]) v = 0.f;
                J.C[m * 256 + col] = v;
            }
        }
    }
}

// 2048 one-qpos blocks. b = bid&7 keeps XCD affinity (working set ~2.3MB fits 4MiB
// private L2; FETCH 51->9.3MB measured). qpos map per-CU balanced (each CU's 8 blocks
// sum to exactly 1028 rows). Inner loops BATCH-3 (6 float4 in flight): +50% MLP over
// batch-2 while fitting the 64-VGPR budget of (256,8) — batch-4 (8 in flight) spills
// (WRITE_SIZE 7.9-22.5MB, verified r1/2/4/6). Spill tripwire: WRITE must stay 2048KB.
__global__ __launch_bounds__(256, 8) void attn_kernel(
    const float* __restrict__ Q, const float* __restrict__ Kp, const float* __restrict__ Vp,
    const float* __restrict__ qres, const int* __restrict__ tm,
    const float* __restrict__ tK, const float* __restrict__ tV,
    const float* __restrict__ g2, const float* __restrict__ b2,
    float* __restrict__ X2) {
    int bid = (int)blockIdx.x;
    int b = bid & 7;                    // XCD-aligned batch
    int i6 = bid >> 3;                  // 0..255
    int jj6 = i6 & 31, a6 = i6 >> 5;
    int q0m = jj6 * 4 + (a6 >> 1);      // 0..127
    int qpos = (a6 & 1) ? q0m : 255 - q0m;
    int tid = threadIdx.x, w = tid >> 6, lane = tid & 63;
    __shared__ float qrow[256];
    __shared__ int   stm[256];
    __shared__ float p[4][264];     // 264: writer lanes spread banks
    __shared__ float opart[4][256];
    __shared__ float denom[4];
    __shared__ float lnws[8];

    int rowbase = (b * 256 + qpos) * 256;
    qrow[tid] = Q[rowbase + tid];
    {
        int t = tm[rowbase + tid];
        stm[tid] = t < 0 ? 0 : (t > 512 ? 512 : t);
    }
    __syncthreads();

    // --- phase 1: scores, k ≡ w (mod 4) per wave — balanced across waves; batch-3
    {
        int h = lane >> 4;
        const float* qr = qrow + lane * 4;
        float q0 = qr[0], q1 = qr[1], q2 = qr[2], q3 = qr[3];
        const float* Kb  = Kp + (size_t)(b << 8) * 256 + lane * 4;
        const float* tKb = tK + lane * 4;
        int nact = (qpos >= w) ? ((qpos - w) >> 2) + 1 : 0;  // #k in {w, w+4, ...} <= qpos
        int i = 0;
        for (; i + 3 <= nact; i += 3) {
            int k0 = w + 4 * i;          // rows k0, k0+4, k0+8
            float4 kv0 = *(const float4*)(Kb + (k0    ) * 256);
            float4 kv1 = *(const float4*)(Kb + (k0 + 4) * 256);
            float4 kv2 = *(const float4*)(Kb + (k0 + 8) * 256);
            float4 t0 = *(const float4*)(tKb + stm[k0    ] * 256);
            float4 t1 = *(const float4*)(tKb + stm[k0 + 4] * 256);
            float4 t2 = *(const float4*)(tKb + stm[k0 + 8] * 256);
            float s0 = q0 * (kv0.x + t0.x) + q1 * (kv0.y + t0.y) + q2 * (kv0.z + t0.z) + q3 * (kv0.w + t0.w);
            float s1 = q0 * (kv1.x + t1.x) + q1 * (kv1.y + t1.y) + q2 * (kv1.z + t1.z) + q3 * (kv1.w + t1.w);
            float s2 = q0 * (kv2.x + t2.x) + q1 * (kv2.y + t2.y) + q2 * (kv2.z + t2.z) + q3 * (kv2.w + t2.w);
            s0 += __shfl_xor(s0, 1, 64); s1 += __shfl_xor(s1, 1, 64); s2 += __shfl_xor(s2, 1, 64);
            s0 += __shfl_xor(s0, 2, 64); s1 += __shfl_xor(s1, 2, 64); s2 += __shfl_xor(s2, 2, 64);
            s0 += __shfl_xor(s0, 4, 64); s1 += __shfl_xor(s1, 4, 64); s2 += __shfl_xor(s2, 4, 64);
            s0 += __shfl_xor(s0, 8, 64); s1 += __shfl_xor(s1, 8, 64); s2 += __shfl_xor(s2, 8, 64);
            if ((lane & 15) == 0) {
                p[h][k0    ] = s0 * 0.125f;
                p[h][k0 + 4] = s1 * 0.125f;
                p[h][k0 + 8] = s2 * 0.125f;
            }
        }
        for (; i < nact; ++i) {
            int k = w + 4 * i;
            float4 kv = *(const float4*)(Kb + k * 256);
            float4 t4 = *(const float4*)(tKb + stm[k] * 256);
            float s = q0 * (kv.x + t4.x) + q1 * (kv.y + t4.y) + q2 * (kv.z + t4.z) + q3 * (kv.w + t4.w);
            s += __shfl_xor(s, 1, 64);
            s += __shfl_xor(s, 2, 64);
            s += __shfl_xor(s, 4, 64);
            s += __shfl_xor(s, 8, 64);
            if ((lane & 15) == 0) p[h][k] = s * 0.125f;
        }
    }
    __syncthreads();

    // --- softmax: wave w owns head w; invalid k (> qpos) masked at read
    {
        float* ph = &p[w][0];
        float v0 = (lane       <= qpos) ? ph[lane      ] : BIG_NEG_F;
        float v1 = (lane + 64  <= qpos) ? ph[lane + 64 ] : BIG_NEG_F;
        float v2 = (lane + 128 <= qpos) ? ph[lane + 128] : BIG_NEG_F;
        float v3 = (lane + 192 <= qpos) ? ph[lane + 192] : BIG_NEG_F;
        float mx = wave_max(fmaxf(fmaxf(v0, v1), fmaxf(v2, v3)));
        float e0 = __expf(v0 - mx), e1 = __expf(v1 - mx), e2 = __expf(v2 - mx), e3 = __expf(v3 - mx);
        ph[lane] = e0; ph[lane + 64] = e1; ph[lane + 128] = e2; ph[lane + 192] = e3;
        float ssum = wave_sum(e0 + e1 + e2 + e3);
        if (lane == 0) denom[w] = ssum;
    }
    __syncthreads();

    // --- phase 3: PV, batch-3 with independent accumulators
    {
        int hh = lane >> 4;                 // head of this lane's 4 dims
        const float* Vb  = Vp + (size_t)(b << 8) * 256 + lane * 4;
        const float* tVb = tV + lane * 4;
        const float* prow = &p[hh][0];
        float4 a0 = {0.f, 0.f, 0.f, 0.f}, a1 = a0, a2 = a0;
        int cnt = (qpos >= w) ? ((qpos - w) >> 2) + 1 : 0;
        int i = 0;
        for (; i + 3 <= cnt; i += 3) {
            int k0 = w + 4 * i;
            float p0 = prow[k0], p1 = prow[k0 + 4], p2 = prow[k0 + 8];
            float4 v0 = *(const float4*)(Vb + (k0    ) * 256);
            float4 v1 = *(const float4*)(Vb + (k0 + 4) * 256);
            float4 v2 = *(const float4*)(Vb + (k0 + 8) * 256);
            float4 u0 = *(const float4*)(tVb + stm[k0    ] * 256);
            float4 u1 = *(const float4*)(tVb + stm[k0 + 4] * 256);
            float4 u2 = *(const float4*)(tVb + stm[k0 + 8] * 256);
            a0.x += p0 * (v0.x + u0.x); a0.y += p0 * (v0.y + u0.y); a0.z += p0 * (v0.z + u0.z); a0.w += p0 * (v0.w + u0.w);
            a1.x += p1 * (v1.x + u1.x); a1.y += p1 * (v1.y + u1.y); a1.z += p1 * (v1.z + u1.z); a1.w += p1 * (v1.w + u1.w);
            a2.x += p2 * (v2.x + u2.x); a2.y += p2 * (v2.y + u2.y); a2.z += p2 * (v2.z + u2.z); a2.w += p2 * (v2.w + u2.w);
        }
        for (; i < cnt; ++i) {
            int k2 = w + 4 * i;
            float pk = prow[k2];
            float4 v = *(const float4*)(Vb + k2 * 256);
            float4 t = *(const float4*)(tVb + stm[k2] * 256);
            a0.x += pk * (v.x + t.x);
            a0.y += pk * (v.y + t.y);
            a0.z += pk * (v.z + t.z);
            a0.w += pk * (v.w + t.w);
        }
        float4 o;
        o.x = a0.x + (a1.x + a2.x);
        o.y = a0.y + (a1.y + a2.y);
        o.z = a0.z + (a1.z + a2.z);
        o.w = a0.w + (a1.w + a2.w);
        *(float4*)&opart[w][lane * 4] = o;
    }
    __syncthreads();

    // --- combine + fused ln2
    {
        int d = tid, h = tid >> 6;
        float tot = opart[0][d] + opart[1][d] + opart[2][d] + opart[3][d];
        float xv = qres[rowbase + d] + tot / denom[h];
        float s = wave_sum(xv);
        if (lane == 0) lnws[w] = s;
        __syncthreads();
        float mean = (lnws[0] + lnws[1] + lnws[2] + lnws[3]) * (1.f / 256.f);
        float dd = xv - mean;
        float s2 = wave_sum(dd * dd);
        if (lane == 0) lnws[4 + w] = s2;
        __syncthreads();
        float var = (lnws[4] + lnws[5] + lnws[6] + lnws[7]) * (1.f / 256.f);
        X2[rowbase + d] = dd / sqrtf(var + 1e-8f) * g2[d] + b2[d];
    }
}

extern "C" void kernel_launch(void* const* d_in, const int* in_sizes, int n_in,
                              void* d_out, int out_size, void* d_ws, size_t ws_size,
                              hipStream_t stream) {
    const unsigned char* mask_raw = (const unsigned char*)d_in[0];
    const float* seq  = (const float*)d_in[1];
    const int*   tm   = (const int*)d_in[3];
    const float* Wq   = (const float*)d_in[5];
    const float* bq   = (const float*)d_in[6];
    const float* Wk   = (const float*)d_in[7];
    const float* bk   = (const float*)d_in[8];
    const float* Wv   = (const float*)d_in[9];
    const float* bv   = (const float*)d_in[10];
    const float* ln1g = (const float*)d_in[11];
    const float* ln1b = (const float*)d_in[12];
    const float* ln2g = (const float*)d_in[13];
    const float* ln2b = (const float*)d_in[14];
    const float* W1   = (const float*)d_in[15];
    const float* b1   = (const float*)d_in[16];
    const float* W2   = (const float*)d_in[17];
    const float* b2   = (const float*)d_in[18];
    const float* posK = (const float*)d_in[19];
    const float* posV = (const float*)d_in[20];
    const float* tK   = (const float*)d_in[21];
    const float* tV   = (const float*)d_in[22];
    const float* lnfg = (const float*)d_in[23];
    const float* lnfb = (const float*)d_in[24];

    const int NEL = 8 * 256 * 256;
    float* x   = (float*)d_ws;
    float* q   = x   + NEL;
    float* Qb  = q   + NEL;
    float* KpB = Qb  + NEL;
    float* VpB = KpB + NEL;
    float* x2  = VpB + NEL;
    float* hb  = x2  + NEL;
    unsigned char* mask = (unsigned char*)(hb + NEL);

    dim3 gQKV(4, 32, 3);   // 384 blocks
    dim3 gFFN(4, 32, 1);   // 128 blocks

    prep_ln_kernel<<<2048, 256, 0, stream>>>(seq, mask_raw, mask, x, q, ln1g, ln1b);
    for (int blk = 0; blk < 2; ++blk) {
        int o1 = blk * 256, oW = blk * 256 * 256;
        GemmJob jq = {q, Wq + oW, bq + o1, nullptr, nullptr, nullptr, Qb, 0};
        GemmJob jk = {x, Wk + oW, bk + o1, posK,    nullptr, nullptr, KpB, 0};
        GemmJob jv = {x, Wv + oW, bv + o1, posV,    nullptr, nullptr, VpB, 0};
        gemm_mfma_kernel<<<gQKV, 256, 0, stream>>>(jq, jk, jv);
        attn_kernel<<<2048, 256, 0, stream>>>(Qb, KpB, VpB, q, tm, tK, tV,
                                              ln2g + o1, ln2b + o1, x2);
        GemmJob f1 = {x2, W1 + oW, b1 + o1, nullptr, nullptr, nullptr, hb, 1};
        gemm_mfma_kernel<<<gFFN, 256, 0, stream>>>(f1, f1, f1);
        GemmJob f2 = {hb, W2 + oW, b2 + o1, nullptr, x2, mask, x, 0};
        gemm_mfma_kernel<<<gFFN, 256, 0, stream>>>(f2, f2, f2);
        if (blk == 0) ln_kernel<<<2048, 256, 0, stream>>>(x, q, ln1g + 256, ln1b + 256);
    }
    ln_kernel<<<2048, 256, 0, stream>>>(x, (float*)d_out, lnfg, lnfb);
}

// Round 15
// 249.276 us; speedup vs baseline: 1.0395x; 1.0395x over previous
//
#include <hip/hip_runtime.h>

#define BIG_NEG_F (-4294967296.0f)

typedef __attribute__((ext_vector_type(8))) short bf16x8;
typedef __attribute__((ext_vector_type(4))) float f32x4;

__device__ __forceinline__ float wave_sum(float v) {
#pragma unroll
    for (int m = 32; m; m >>= 1) v += __shfl_xor(v, m, 64);
    return v;
}
__device__ __forceinline__ float wave_max(float v) {
#pragma unroll
    for (int m = 32; m; m >>= 1) v = fmaxf(v, __shfl_xor(v, m, 64));
    return v;
}

__device__ __forceinline__ unsigned int pack2(float a, float b) {
    return (__float_as_uint(b) & 0xffff0000u) | (__float_as_uint(a) >> 16);
}
__device__ __forceinline__ float hipart(float x) {
    return __uint_as_float(__float_as_uint(x) & 0xffff0000u);
}
// split two float4 into hi/lo bf16 (truncation split: hi exact-representable, lo = residual)
__device__ __forceinline__ void store_pair(unsigned short* hp, unsigned short* lp,
                                           float4 a, float4 b) {
    uint4 h;
    h.x = pack2(a.x, a.y); h.y = pack2(a.z, a.w);
    h.z = pack2(b.x, b.y); h.w = pack2(b.z, b.w);
    float lax = a.x - hipart(a.x), lay = a.y - hipart(a.y);
    float laz = a.z - hipart(a.z), law = a.w - hipart(a.w);
    float lbx = b.x - hipart(b.x), lby = b.y - hipart(b.y);
    float lbz = b.z - hipart(b.z), lbw = b.w - hipart(b.w);
    uint4 l;
    l.x = pack2(lax, lay); l.y = pack2(laz, law);
    l.z = pack2(lbx, lby); l.w = pack2(lbz, lbw);
    *(uint4*)hp = h;
    *(uint4*)lp = l;
}

// Fused: detect mask layout (u8/i32/i64) from first 2048 bytes, normalize this row's bit,
// x = seq*keep, q = ln1(x). One block per row.
__global__ __launch_bounds__(256) void prep_ln_kernel(const float* __restrict__ seq,
                                                      const unsigned char* __restrict__ mraw,
                                                      unsigned char* __restrict__ mout,
                                                      float* __restrict__ X, float* __restrict__ Q,
                                                      const float* __restrict__ g,
                                                      const float* __restrict__ be) {
    __shared__ int flags[2];
    __shared__ float ws[8];
    int row = blockIdx.x, tid = threadIdx.x;
    if (tid == 0) { flags[0] = 0; flags[1] = 0; }
    __syncthreads();
    for (int i = tid; i < 2048; i += 256) {
        if (mraw[i]) {
            if (i & 3) atomicOr(&flags[0], 1);
            else if (i & 4) atomicOr(&flags[1], 1);
        }
    }
    __syncthreads();
    int mode = flags[0] ? 0 : (flags[1] ? 1 : 2);  // 0=u8, 1=i32, 2=i64
    unsigned char mrow = (mode == 0) ? mraw[row] : (mode == 1) ? mraw[row * 4] : mraw[row * 8];
    if (tid == 0) mout[row] = mrow ? 1 : 0;
    int idx = row * 256 + tid;
    int w = tid >> 6, lane = tid & 63;
    float v = mrow ? 0.f : seq[idx];
    X[idx] = v;
    float s = wave_sum(v);
    if (lane == 0) ws[w] = s;
    __syncthreads();
    float mean = (ws[0] + ws[1] + ws[2] + ws[3]) * (1.f / 256.f);
    float d = v - mean;
    float s2 = wave_sum(d * d);
    if (lane == 0) ws[4 + w] = s2;
    __syncthreads();
    float var = (ws[4] + ws[5] + ws[6] + ws[7]) * (1.f / 256.f);
    Q[idx] = d / sqrtf(var + 1e-8f) * g[tid] + be[tid];
}

// row layernorm over H=256, one block per row; shfl reductions (2 barriers)
__global__ __launch_bounds__(256) void ln_kernel(const float* __restrict__ X, float* __restrict__ Y,
                                                 const float* __restrict__ g,
                                                 const float* __restrict__ be) {
    __shared__ float ws[8];
    int row = blockIdx.x, tid = threadIdx.x;
    int idx = row * 256 + tid;
    int w = tid >> 6, lane = tid & 63;
    float v = X[idx];
    float s = wave_sum(v);
    if (lane == 0) ws[w] = s;
    __syncthreads();
    float mean = (ws[0] + ws[1] + ws[2] + ws[3]) * (1.f / 256.f);
    float d = v - mean;
    float s2 = wave_sum(d * d);
    if (lane == 0) ws[4 + w] = s2;
    __syncthreads();
    float var = (ws[4] + ws[5] + ws[6] + ws[7]) * (1.f / 256.f);
    Y[idx] = d / sqrtf(var + 1e-8f) * g[tid] + be[tid];
}

struct GemmJob {
    const float* A;            // [2048,256]
    const float* W;            // [256,256] row-major (out,in)
    const float* bias;         // [256]
    const float* pos;          // [256,256] per-position add, or null
    const float* res;          // residual add, or null
    const unsigned char* maskm;// row mask (zero out), or null
    float* C;                  // [2048,256]
    int relu;
};

// MFMA GEMM (r11 structure — best measured): C = A·W^T via split-precision bf16
// (A·B ≈ Ah·Bh + Ah·Bl + Al·Bh, rel err ~2^-16). 64x64 tile, BK=64, 4 waves as 2x2.
// r12/r13: direct-fragment loads are transaction-bound and pre-splitting buys nothing.
// Fragment layouts HW-verified r11. LDS rows padded to 72 ushorts. Register-prefetch.
__global__ __launch_bounds__(256) void gemm_mfma_kernel(GemmJob j0, GemmJob j1, GemmJob j2) {
    GemmJob J = (blockIdx.z == 0) ? j0 : (blockIdx.z == 1 ? j1 : j2);
    __shared__ unsigned short Ah[64][72], Al[64][72], Wh[64][72], Wl[64][72];
    int tid = threadIdx.x;
    int n0 = blockIdx.x * 64, m0 = blockIdx.y * 64;
    int w = tid >> 6, lane = tid & 63;
    int wm = w >> 1, wn = w & 1;
    int srow = tid >> 2, sq = tid & 3;          // staging: row 0..63, k-quarter 0..3
    const float* Asrc = J.A + (m0 + srow) * 256 + sq * 16;
    const float* Wsrc = J.W + (n0 + srow) * 256 + sq * 16;
    float4 ar0 = *(const float4*)(Asrc),      ar1 = *(const float4*)(Asrc + 4),
           ar2 = *(const float4*)(Asrc + 8),  ar3 = *(const float4*)(Asrc + 12);
    float4 wr0 = *(const float4*)(Wsrc),      wr1 = *(const float4*)(Wsrc + 4),
           wr2 = *(const float4*)(Wsrc + 8),  wr3 = *(const float4*)(Wsrc + 12);
    f32x4 acc[2][2] = {};
    int r15 = lane & 15, hgrp = (lane >> 4) << 3;
    for (int kt = 0; kt < 4; ++kt) {
        if (kt) __syncthreads();                // previous compute done before overwrite
        store_pair(&Ah[srow][sq * 16],     &Al[srow][sq * 16],     ar0, ar1);
        store_pair(&Ah[srow][sq * 16 + 8], &Al[srow][sq * 16 + 8], ar2, ar3);
        store_pair(&Wh[srow][sq * 16],     &Wl[srow][sq * 16],     wr0, wr1);
        store_pair(&Wh[srow][sq * 16 + 8], &Wl[srow][sq * 16 + 8], wr2, wr3);
        __syncthreads();
        if (kt < 3) {                           // prefetch next K-tile; retires under MFMAs
            int ko = (kt + 1) * 64;
            ar0 = *(const float4*)(Asrc + ko);      ar1 = *(const float4*)(Asrc + ko + 4);
            ar2 = *(const float4*)(Asrc + ko + 8);  ar3 = *(const float4*)(Asrc + ko + 12);
            wr0 = *(const float4*)(Wsrc + ko);      wr1 = *(const float4*)(Wsrc + ko + 4);
            wr2 = *(const float4*)(Wsrc + ko + 8);  wr3 = *(const float4*)(Wsrc + ko + 12);
        }
#pragma unroll
        for (int s = 0; s < 2; ++s) {
            int ko = s * 32 + hgrp;
            bf16x8 ah0 = *(const bf16x8*)&Ah[wm * 32 + r15][ko];
            bf16x8 ah1 = *(const bf16x8*)&Ah[wm * 32 + 16 + r15][ko];
            bf16x8 al0 = *(const bf16x8*)&Al[wm * 32 + r15][ko];
            bf16x8 al1 = *(const bf16x8*)&Al[wm * 32 + 16 + r15][ko];
            bf16x8 bh0 = *(const bf16x8*)&Wh[wn * 32 + r15][ko];
            bf16x8 bh1 = *(const bf16x8*)&Wh[wn * 32 + 16 + r15][ko];
            bf16x8 bl0 = *(const bf16x8*)&Wl[wn * 32 + r15][ko];
            bf16x8 bl1 = *(const bf16x8*)&Wl[wn * 32 + 16 + r15][ko];
            acc[0][0] = __builtin_amdgcn_mfma_f32_16x16x32_bf16(ah0, bh0, acc[0][0], 0, 0, 0);
            acc[0][0] = __builtin_amdgcn_mfma_f32_16x16x32_bf16(ah0, bl0, acc[0][0], 0, 0, 0);
            acc[0][0] = __builtin_amdgcn_mfma_f32_16x16x32_bf16(al0, bh0, acc[0][0], 0, 0, 0);
            acc[0][1] = __builtin_amdgcn_mfma_f32_16x16x32_bf16(ah0, bh1, acc[0][1], 0, 0, 0);
            acc[0][1] = __builtin_amdgcn_mfma_f32_16x16x32_bf16(ah0, bl1, acc[0][1], 0, 0, 0);
            acc[0][1] = __builtin_amdgcn_mfma_f32_16x16x32_bf16(al0, bh1, acc[0][1], 0, 0, 0);
            acc[1][0] = __builtin_amdgcn_mfma_f32_16x16x32_bf16(ah1, bh0, acc[1][0], 0, 0, 0);
            acc[1][0] = __builtin_amdgcn_mfma_f32_16x16x32_bf16(ah1, bl0, acc[1][0], 0, 0, 0);
            acc[1][0] = __builtin_amdgcn_mfma_f32_16x16x32_bf16(al1, bh0, acc[1][0], 0, 0, 0);
            acc[1][1] = __builtin_amdgcn_mfma_f32_16x16x32_bf16(ah1, bh1, acc[1][1], 0, 0, 0);
            acc[1][1] = __builtin_amdgcn_mfma_f32_16x16x32_bf16(ah1, bl1, acc[1][1], 0, 0, 0);
            acc[1][1] = __builtin_amdgcn_mfma_f32_16x16x32_bf16(al1, bh1, acc[1][1], 0, 0, 0);
        }
    }
    // epilogue: C/D layout col=lane&15, row=(lane>>4)*4+rr
#pragma unroll
    for (int mf = 0; mf < 2; ++mf) {
#pragma unroll
        for (int nf = 0; nf < 2; ++nf) {
            int col = n0 + wn * 32 + nf * 16 + r15;
            int rowb = m0 + wm * 32 + mf * 16 + ((lane >> 4) << 2);
            float bcol = J.bias[col];
            f32x4 a = acc[mf][nf];
#pragma unroll
            for (int rr = 0; rr < 4; ++rr) {
                int m = rowb + rr;
                float v = a[rr] + bcol;
                if (J.pos) v += J.pos[(m & 255) * 256 + col];
                if (J.relu) v = fmaxf(v, 0.f);
                if (J.res) v += J.res[m * 256 + col];
                if (J.maskm && J.maskm[m]) v = 0.f;
                J.C[m * 256 + col] = v;
            }
        }
    }
}

// PAIRED attn: one block handles qA=2P, qB=2P+1 in the SAME inner loops, sharing the
// K-row and V-row loads (tK/tV gathers are per-q, unshared): per k, 6 rows instead of
// 8 -> 25% L2 traffic cut (1.05GB -> 0.79GB, floor 30->23us). 1024 blocks, b=bid&7
// keeps XCD affinity. Pair map: j=i6&31, a=i6>>5, base=2j+(a>>1),
// P=(a&1)?base:127-base — bijective over [0,128); each CU's 4 blocks get pairs
// {127-2j, 2j, 126-2j, 2j+1}: per-CU row sum = 4*254+12 = 1028, exactly uniform.
// launch_bounds(256,4): 128-VGPR budget (4 blocks/CU is all the grid provides anyway)
// -> the 6-in-flight inner loop (~55 VGPR) cannot spill. Tripwire: WRITE == 2048KB.
// Softmax writes e=0 for invalid k so phase 3 sweeps both q over qB's superset range.
__global__ __launch_bounds__(256, 4) void attn_kernel(
    const float* __restrict__ Q, const float* __restrict__ Kp, const float* __restrict__ Vp,
    const float* __restrict__ qres, const int* __restrict__ tm,
    const float* __restrict__ tK, const float* __restrict__ tV,
    const float* __restrict__ g2, const float* __restrict__ b2,
    float* __restrict__ X2) {
    int bid = (int)blockIdx.x;
    int b = bid & 7;                    // XCD-aligned batch
    int i6 = bid >> 3;                  // 0..127
    int j = i6 & 31, a = i6 >> 5;
    int base = 2 * j + (a >> 1);        // 0..63
    int P = (a & 1) ? base : 127 - base;
    int qA = 2 * P, qB = 2 * P + 1;
    int tid = threadIdx.x, w = tid >> 6, lane = tid & 63;
    __shared__ float qrow[2][256];
    __shared__ int   stm[2][256];
    __shared__ float p[2][4][264];
    __shared__ float opart[2][4][256];
    __shared__ float denom[2][4];
    __shared__ float lnws[2][8];

    int rowbaseA = (b * 256 + qA) * 256;
    int rowbaseB = (b * 256 + qB) * 256;
    qrow[0][tid] = Q[rowbaseA + tid];
    qrow[1][tid] = Q[rowbaseB + tid];
    {
        int tA = tm[rowbaseA + tid];
        int tB = tm[rowbaseB + tid];
        stm[0][tid] = tA < 0 ? 0 : (tA > 512 ? 512 : tA);
        stm[1][tid] = tB < 0 ? 0 : (tB > 512 ? 512 : tB);
    }
    __syncthreads();

    // --- phase 1: scores for BOTH q over qB's range, k ≡ w (mod 4); batch-2
    {
        int h = lane >> 4;
        const float* qrA = &qrow[0][lane * 4];
        const float* qrB = &qrow[1][lane * 4];
        float qA0 = qrA[0], qA1 = qrA[1], qA2 = qrA[2], qA3 = qrA[3];
        float qB0 = qrB[0], qB1 = qrB[1], qB2 = qrB[2], qB3 = qrB[3];
        const float* Kb  = Kp + (size_t)(b << 8) * 256 + lane * 4;
        const float* tKb = tK + lane * 4;
        int nact = (qB >= w) ? ((qB - w) >> 2) + 1 : 0;
        int i = 0;
        for (; i + 2 <= nact; i += 2) {
            int k0 = w + 4 * i, k1 = k0 + 4;
            float4 kv0 = *(const float4*)(Kb + k0 * 256);
            float4 kv1 = *(const float4*)(Kb + k1 * 256);
            float4 tA0 = *(const float4*)(tKb + stm[0][k0] * 256);
            float4 tA1 = *(const float4*)(tKb + stm[0][k1] * 256);
            float4 tB0 = *(const float4*)(tKb + stm[1][k0] * 256);
            float4 tB1 = *(const float4*)(tKb + stm[1][k1] * 256);
            float sA0 = qA0 * (kv0.x + tA0.x) + qA1 * (kv0.y + tA0.y) + qA2 * (kv0.z + tA0.z) + qA3 * (kv0.w + tA0.w);
            float sA1 = qA0 * (kv1.x + tA1.x) + qA1 * (kv1.y + tA1.y) + qA2 * (kv1.z + tA1.z) + qA3 * (kv1.w + tA1.w);
            float sB0 = qB0 * (kv0.x + tB0.x) + qB1 * (kv0.y + tB0.y) + qB2 * (kv0.z + tB0.z) + qB3 * (kv0.w + tB0.w);
            float sB1 = qB0 * (kv1.x + tB1.x) + qB1 * (kv1.y + tB1.y) + qB2 * (kv1.z + tB1.z) + qB3 * (kv1.w + tB1.w);
            sA0 += __shfl_xor(sA0, 1, 64); sA1 += __shfl_xor(sA1, 1, 64);
            sB0 += __shfl_xor(sB0, 1, 64); sB1 += __shfl_xor(sB1, 1, 64);
            sA0 += __shfl_xor(sA0, 2, 64); sA1 += __shfl_xor(sA1, 2, 64);
            sB0 += __shfl_xor(sB0, 2, 64); sB1 += __shfl_xor(sB1, 2, 64);
            sA0 += __shfl_xor(sA0, 4, 64); sA1 += __shfl_xor(sA1, 4, 64);
            sB0 += __shfl_xor(sB0, 4, 64); sB1 += __shfl_xor(sB1, 4, 64);
            sA0 += __shfl_xor(sA0, 8, 64); sA1 += __shfl_xor(sA1, 8, 64);
            sB0 += __shfl_xor(sB0, 8, 64); sB1 += __shfl_xor(sB1, 8, 64);
            if ((lane & 15) == 0) {
                p[0][h][k0] = sA0 * 0.125f;
                p[0][h][k1] = sA1 * 0.125f;
                p[1][h][k0] = sB0 * 0.125f;
                p[1][h][k1] = sB1 * 0.125f;
            }
        }
        if (i < nact) {
            int k = w + 4 * i;
            float4 kv = *(const float4*)(Kb + k * 256);
            float4 tA4 = *(const float4*)(tKb + stm[0][k] * 256);
            float4 tB4 = *(const float4*)(tKb + stm[1][k] * 256);
            float sA = qA0 * (kv.x + tA4.x) + qA1 * (kv.y + tA4.y) + qA2 * (kv.z + tA4.z) + qA3 * (kv.w + tA4.w);
            float sB = qB0 * (kv.x + tB4.x) + qB1 * (kv.y + tB4.y) + qB2 * (kv.z + tB4.z) + qB3 * (kv.w + tB4.w);
            sA += __shfl_xor(sA, 1, 64); sB += __shfl_xor(sB, 1, 64);
            sA += __shfl_xor(sA, 2, 64); sB += __shfl_xor(sB, 2, 64);
            sA += __shfl_xor(sA, 4, 64); sB += __shfl_xor(sB, 4, 64);
            sA += __shfl_xor(sA, 8, 64); sB += __shfl_xor(sB, 8, 64);
            if ((lane & 15) == 0) {
                p[0][h][k] = sA * 0.125f;
                p[1][h][k] = sB * 0.125f;
            }
        }
    }
    __syncthreads();

    // --- softmax: wave w owns head w for BOTH q; invalid k -> e = 0 (enables shared phase 3)
    {
        float* phA = &p[0][w][0];
        float* phB = &p[1][w][0];
        float a0 = (lane       <= qA) ? phA[lane      ] : BIG_NEG_F;
        float a1 = (lane + 64  <= qA) ? phA[lane + 64 ] : BIG_NEG_F;
        float a2 = (lane + 128 <= qA) ? phA[lane + 128] : BIG_NEG_F;
        float a3 = (lane + 192 <= qA) ? phA[lane + 192] : BIG_NEG_F;
        float b0 = (lane       <= qB) ? phB[lane      ] : BIG_NEG_F;
        float b1 = (lane + 64  <= qB) ? phB[lane + 64 ] : BIG_NEG_F;
        float b2v = (lane + 128 <= qB) ? phB[lane + 128] : BIG_NEG_F;
        float b3 = (lane + 192 <= qB) ? phB[lane + 192] : BIG_NEG_F;
        float mxA = wave_max(fmaxf(fmaxf(a0, a1), fmaxf(a2, a3)));
        float mxB = wave_max(fmaxf(fmaxf(b0, b1), fmaxf(b2v, b3)));
        float eA0 = (lane       <= qA) ? __expf(a0 - mxA) : 0.f;
        float eA1 = (lane + 64  <= qA) ? __expf(a1 - mxA) : 0.f;
        float eA2 = (lane + 128 <= qA) ? __expf(a2 - mxA) : 0.f;
        float eA3 = (lane + 192 <= qA) ? __expf(a3 - mxA) : 0.f;
        float eB0 = (lane       <= qB) ? __expf(b0 - mxB) : 0.f;
        float eB1 = (lane + 64  <= qB) ? __expf(b1 - mxB) : 0.f;
        float eB2 = (lane + 128 <= qB) ? __expf(b2v - mxB) : 0.f;
        float eB3 = (lane + 192 <= qB) ? __expf(b3 - mxB) : 0.f;
        phA[lane] = eA0; phA[lane + 64] = eA1; phA[lane + 128] = eA2; phA[lane + 192] = eA3;
        phB[lane] = eB0; phB[lane + 64] = eB1; phB[lane + 128] = eB2; phB[lane + 192] = eB3;
        float sumA = wave_sum(eA0 + eA1 + eA2 + eA3);
        float sumB = wave_sum(eB0 + eB1 + eB2 + eB3);
        if (lane == 0) { denom[0][w] = sumA; denom[1][w] = sumB; }
    }
    __syncthreads();

    // --- phase 3: PV for BOTH q over qB's range (p_A is 0 beyond qA); batch-2
    {
        int hh = lane >> 4;
        const float* Vb  = Vp + (size_t)(b << 8) * 256 + lane * 4;
        const float* tVb = tV + lane * 4;
        const float* prA = &p[0][hh][0];
        const float* prB = &p[1][hh][0];
        float4 aA0 = {0.f, 0.f, 0.f, 0.f}, aA1 = aA0, aB0 = aA0, aB1 = aA0;
        int cnt = (qB >= w) ? ((qB - w) >> 2) + 1 : 0;
        int i = 0;
        for (; i + 2 <= cnt; i += 2) {
            int k0 = w + 4 * i, k1 = k0 + 4;
            float pA0 = prA[k0], pA1 = prA[k1], pB0 = prB[k0], pB1 = prB[k1];
            float4 v0 = *(const float4*)(Vb + k0 * 256);
            float4 v1 = *(const float4*)(Vb + k1 * 256);
            float4 uA0 = *(const float4*)(tVb + stm[0][k0] * 256);
            float4 uA1 = *(const float4*)(tVb + stm[0][k1] * 256);
            float4 uB0 = *(const float4*)(tVb + stm[1][k0] * 256);
            float4 uB1 = *(const float4*)(tVb + stm[1][k1] * 256);
            aA0.x += pA0 * (v0.x + uA0.x); aA0.y += pA0 * (v0.y + uA0.y); aA0.z += pA0 * (v0.z + uA0.z); aA0.w += pA0 * (v0.w + uA0.w);
            aA1.x += pA1 * (v1.x + uA1.x); aA1.y += pA1 * (v1.y + uA1.y); aA1.z += pA1 * (v1.z + uA1.z); aA1.w += pA1 * (v1.w + uA1.w);
            aB0.x += pB0 * (v0.x + uB0.x); aB0.y += pB0 * (v0.y + uB0.y); aB0.z += pB0 * (v0.z + uB0.z); aB0.w += pB0 * (v0.w + uB0.w);
            aB1.x += pB1 * (v1.x + uB1.x); aB1.y += pB1 * (v1.y + uB1.y); aB1.z += pB1 * (v1.z + uB1.z); aB1.w += pB1 * (v1.w + uB1.w);
        }
        if (i < cnt) {
            int k2 = w + 4 * i;
            float pA = prA[k2], pB = prB[k2];
            float4 v = *(const float4*)(Vb + k2 * 256);
            float4 uA = *(const float4*)(tVb + stm[0][k2] * 256);
            float4 uB = *(const float4*)(tVb + stm[1][k2] * 256);
            aA0.x += pA * (v.x + uA.x); aA0.y += pA * (v.y + uA.y);
            aA0.z += pA * (v.z + uA.z); aA0.w += pA * (v.w + uA.w);
            aB0.x += pB * (v.x + uB.x); aB0.y += pB * (v.y + uB.y);
            aB0.z += pB * (v.z + uB.z); aB0.w += pB * (v.w + uB.w);
        }
        float4 oA, oB;
        oA.x = aA0.x + aA1.x; oA.y = aA0.y + aA1.y; oA.z = aA0.z + aA1.z; oA.w = aA0.w + aA1.w;
        oB.x = aB0.x + aB1.x; oB.y = aB0.y + aB1.y; oB.z = aB0.z + aB1.z; oB.w = aB0.w + aB1.w;
        *(float4*)&opart[0][w][lane * 4] = oA;
        *(float4*)&opart[1][w][lane * 4] = oB;
    }
    __syncthreads();

    // --- combine + fused ln2 for both rows (parallel per thread, 2 barriers)
    {
        int d = tid, h = tid >> 6;
        float totA = opart[0][0][d] + opart[0][1][d] + opart[0][2][d] + opart[0][3][d];
        float totB = opart[1][0][d] + opart[1][1][d] + opart[1][2][d] + opart[1][3][d];
        float xvA = qres[rowbaseA + d] + totA / denom[0][h];
        float xvB = qres[rowbaseB + d] + totB / denom[1][h];
        float sA = wave_sum(xvA);
        float sB = wave_sum(xvB);
        if (lane == 0) { lnws[0][w] = sA; lnws[1][w] = sB; }
        __syncthreads();
        float meanA = (lnws[0][0] + lnws[0][1] + lnws[0][2] + lnws[0][3]) * (1.f / 256.f);
        float meanB = (lnws[1][0] + lnws[1][1] + lnws[1][2] + lnws[1][3]) * (1.f / 256.f);
        float ddA = xvA - meanA, ddB = xvB - meanB;
        float s2A = wave_sum(ddA * ddA);
        float s2B = wave_sum(ddB * ddB);
        if (lane == 0) { lnws[0][4 + w] = s2A; lnws[1][4 + w] = s2B; }
        __syncthreads();
        float varA = (lnws[0][4] + lnws[0][5] + lnws[0][6] + lnws[0][7]) * (1.f / 256.f);
        float varB = (lnws[1][4] + lnws[1][5] + lnws[1][6] + lnws[1][7]) * (1.f / 256.f);
        float gg = g2[d], bb = b2[d];
        X2[rowbaseA + d] = ddA / sqrtf(varA + 1e-8f) * gg + bb;
        X2[rowbaseB + d] = ddB / sqrtf(varB + 1e-8f) * gg + bb;
    }
}

extern "C" void kernel_launch(void* const* d_in, const int* in_sizes, int n_in,
                              void* d_out, int out_size, void* d_ws, size_t ws_size,
                              hipStream_t stream) {
    const unsigned char* mask_raw = (const unsigned char*)d_in[0];
    const float* seq  = (const float*)d_in[1];
    const int*   tm   = (const int*)d_in[3];
    const float* Wq   = (const float*)d_in[5];
    const float* bq   = (const float*)d_in[6];
    const float* Wk   = (const float*)d_in[7];
    const float* bk   = (const float*)d_in[8];
    const float* Wv   = (const float*)d_in[9];
    const float* bv   = (const float*)d_in[10];
    const float* ln1g = (const float*)d_in[11];
    const float* ln1b = (const float*)d_in[12];
    const float* ln2g = (const float*)d_in[13];
    const float* ln2b = (const float*)d_in[14];
    const float* W1   = (const float*)d_in[15];
    const float* b1   = (const float*)d_in[16];
    const float* W2   = (const float*)d_in[17];
    const float* b2   = (const float*)d_in[18];
    const float* posK = (const float*)d_in[19];
    const float* posV = (const float*)d_in[20];
    const float* tK   = (const float*)d_in[21];
    const float* tV   = (const float*)d_in[22];
    const float* lnfg = (const float*)d_in[23];
    const float* lnfb = (const float*)d_in[24];

    const int NEL = 8 * 256 * 256;
    float* x   = (float*)d_ws;
    float* q   = x   + NEL;
    float* Qb  = q   + NEL;
    float* KpB = Qb  + NEL;
    float* VpB = KpB + NEL;
    float* x2  = VpB + NEL;
    float* hb  = x2  + NEL;
    unsigned char* mask = (unsigned char*)(hb + NEL);

    dim3 gQKV(4, 32, 3);   // 384 blocks
    dim3 gFFN(4, 32, 1);   // 128 blocks

    prep_ln_kernel<<<2048, 256, 0, stream>>>(seq, mask_raw, mask, x, q, ln1g, ln1b);
    for (int blk = 0; blk < 2; ++blk) {
        int o1 = blk * 256, oW = blk * 256 * 256;
        GemmJob jq = {q, Wq + oW, bq + o1, nullptr, nullptr, nullptr, Qb, 0};
        GemmJob jk = {x, Wk + oW, bk + o1, posK,    nullptr, nullptr, KpB, 0};
        GemmJob jv = {x, Wv + oW, bv + o1, posV,    nullptr, nullptr, VpB, 0};
        gemm_mfma_kernel<<<gQKV, 256, 0, stream>>>(jq, jk, jv);
        attn_kernel<<<1024, 256, 0, stream>>>(Qb, KpB, VpB, q, tm, tK, tV,
                                              ln2g + o1, ln2b + o1, x2);
        GemmJob f1 = {x2, W1 + oW, b1 + o1, nullptr, nullptr, nullptr, hb, 1};
        gemm_mfma_kernel<<<gFFN, 256, 0, stream>>>(f1, f1, f1);
        GemmJob f2 = {hb, W2 + oW, b2 + o1, nullptr, x2, mask, x, 0};
        gemm_mfma_kernel<<<gFFN, 256, 0, stream>>>(f2, f2, f2);
        if (blk == 0) ln_kernel<<<2048, 256, 0, stream>>>(x, q, ln1g + 256, ln1b + 256);
    }
    ln_kernel<<<2048, 256, 0, stream>>>(x, (float*)d_out, lnfg, lnfb);
}

// Round 16
// 236.793 us; speedup vs baseline: 1.0943x; 1.0527x over previous
//
#include <hip/hip_runtime.h>

#define BIG_NEG_F (-4294967296.0f)

typedef __attribute__((ext_vector_type(8))) short bf16x8;
typedef __attribute__((ext_vector_type(4))) float f32x4;

__device__ __forceinline__ float wave_sum(float v) {
#pragma unroll
    for (int m = 32; m; m >>= 1) v += __shfl_xor(v, m, 64);
    return v;
}
__device__ __forceinline__ float wave_max(float v) {
#pragma unroll
    for (int m = 32; m; m >>= 1) v = fmaxf(v, __shfl_xor(v, m, 64));
    return v;
}

__device__ __forceinline__ unsigned int pack2(float a, float b) {
    return (__float_as_uint(b) & 0xffff0000u) | (__float_as_uint(a) >> 16);
}
__device__ __forceinline__ float hipart(float x) {
    return __uint_as_float(__float_as_uint(x) & 0xffff0000u);
}
// split two float4 into hi/lo bf16 (truncation split: hi exact-representable, lo = residual)
__device__ __forceinline__ void store_pair(unsigned short* hp, unsigned short* lp,
                                           float4 a, float4 b) {
    uint4 h;
    h.x = pack2(a.x, a.y); h.y = pack2(a.z, a.w);
    h.z = pack2(b.x, b.y); h.w = pack2(b.z, b.w);
    float lax = a.x - hipart(a.x), lay = a.y - hipart(a.y);
    float laz = a.z - hipart(a.z), law = a.w - hipart(a.w);
    float lbx = b.x - hipart(b.x), lby = b.y - hipart(b.y);
    float lbz = b.z - hipart(b.z), lbw = b.w - hipart(b.w);
    uint4 l;
    l.x = pack2(lax, lay); l.y = pack2(laz, law);
    l.z = pack2(lbx, lby); l.w = pack2(lbz, lbw);
    *(uint4*)hp = h;
    *(uint4*)lp = l;
}

// Fused: detect mask layout (u8/i32/i64) from first 2048 bytes, normalize this row's bit,
// x = seq*keep, q = ln1(x). One block per row.
__global__ __launch_bounds__(256) void prep_ln_kernel(const float* __restrict__ seq,
                                                      const unsigned char* __restrict__ mraw,
                                                      unsigned char* __restrict__ mout,
                                                      float* __restrict__ X, float* __restrict__ Q,
                                                      const float* __restrict__ g,
                                                      const float* __restrict__ be) {
    __shared__ int flags[2];
    __shared__ float ws[8];
    int row = blockIdx.x, tid = threadIdx.x;
    if (tid == 0) { flags[0] = 0; flags[1] = 0; }
    __syncthreads();
    for (int i = tid; i < 2048; i += 256) {
        if (mraw[i]) {
            if (i & 3) atomicOr(&flags[0], 1);
            else if (i & 4) atomicOr(&flags[1], 1);
        }
    }
    __syncthreads();
    int mode = flags[0] ? 0 : (flags[1] ? 1 : 2);  // 0=u8, 1=i32, 2=i64
    unsigned char mrow = (mode == 0) ? mraw[row] : (mode == 1) ? mraw[row * 4] : mraw[row * 8];
    if (tid == 0) mout[row] = mrow ? 1 : 0;
    int idx = row * 256 + tid;
    int w = tid >> 6, lane = tid & 63;
    float v = mrow ? 0.f : seq[idx];
    X[idx] = v;
    float s = wave_sum(v);
    if (lane == 0) ws[w] = s;
    __syncthreads();
    float mean = (ws[0] + ws[1] + ws[2] + ws[3]) * (1.f / 256.f);
    float d = v - mean;
    float s2 = wave_sum(d * d);
    if (lane == 0) ws[4 + w] = s2;
    __syncthreads();
    float var = (ws[4] + ws[5] + ws[6] + ws[7]) * (1.f / 256.f);
    Q[idx] = d / sqrtf(var + 1e-8f) * g[tid] + be[tid];
}

// row layernorm over H=256, one block per row; shfl reductions (2 barriers)
__global__ __launch_bounds__(256) void ln_kernel(const float* __restrict__ X, float* __restrict__ Y,
                                                 const float* __restrict__ g,
                                                 const float* __restrict__ be) {
    __shared__ float ws[8];
    int row = blockIdx.x, tid = threadIdx.x;
    int idx = row * 256 + tid;
    int w = tid >> 6, lane = tid & 63;
    float v = X[idx];
    float s = wave_sum(v);
    if (lane == 0) ws[w] = s;
    __syncthreads();
    float mean = (ws[0] + ws[1] + ws[2] + ws[3]) * (1.f / 256.f);
    float d = v - mean;
    float s2 = wave_sum(d * d);
    if (lane == 0) ws[4 + w] = s2;
    __syncthreads();
    float var = (ws[4] + ws[5] + ws[6] + ws[7]) * (1.f / 256.f);
    Y[idx] = d / sqrtf(var + 1e-8f) * g[tid] + be[tid];
}

struct GemmJob {
    const float* A;            // [2048,256]
    const float* W;            // [256,256] row-major (out,in)
    const float* bias;         // [256]
    const float* pos;          // [256,256] per-position add, or null
    const float* res;          // residual add, or null
    const unsigned char* maskm;// row mask (zero out), or null
    float* C;                  // [2048,256]
    int relu;
};

// MFMA GEMM, 32x64 tile (was 64x64): doubles block count for occupancy — dispatch cost
// was ~17us vs ~3us compute, exposed critical path at 0.5-1.5 blocks/CU (FFN had half
// the GPU idle). 4 waves as 2Mx2N, each wave 16x32 (2 frags, 12 MFMA/K-tile). BK=64,
// split-precision bf16 (A·B ≈ Ah·Bh + Ah·Bl + Al·Bh, rel err ~2^-16), fragment layouts
// HW-verified r11. LDS 27.6KB -> 2 blocks/CU co-resident. Register-prefetch of next
// K-tile under the MFMAs. (r12/r13: direct-fragment loads and pre-splitting both fail.)
__global__ __launch_bounds__(256) void gemm_mfma_kernel(GemmJob j0, GemmJob j1, GemmJob j2) {
    GemmJob J = (blockIdx.z == 0) ? j0 : (blockIdx.z == 1 ? j1 : j2);
    __shared__ unsigned short Ah[32][72], Al[32][72], Wh[64][72], Wl[64][72];
    int tid = threadIdx.x;
    int n0 = blockIdx.x * 64, m0 = blockIdx.y * 32;
    int w = tid >> 6, lane = tid & 63;
    int wm = w >> 1, wn = w & 1;
    int rowA = tid >> 3, kA = (tid & 7) * 8;    // A staging: 32 rows x 64 k, 8 floats/thread
    int rowW = tid >> 2, kW = (tid & 3) * 16;   // W staging: 64 rows x 64 k, 16 floats/thread
    const float* Asrc = J.A + (m0 + rowA) * 256 + kA;
    const float* Wsrc = J.W + (n0 + rowW) * 256 + kW;
    float4 ar0 = *(const float4*)(Asrc), ar1 = *(const float4*)(Asrc + 4);
    float4 wr0 = *(const float4*)(Wsrc),      wr1 = *(const float4*)(Wsrc + 4),
           wr2 = *(const float4*)(Wsrc + 8),  wr3 = *(const float4*)(Wsrc + 12);
    f32x4 acc[2] = {};
    int r15 = lane & 15, hgrp = (lane >> 4) << 3;
    for (int kt = 0; kt < 4; ++kt) {
        if (kt) __syncthreads();                // previous compute done before overwrite
        store_pair(&Ah[rowA][kA],     &Al[rowA][kA],     ar0, ar1);
        store_pair(&Wh[rowW][kW],     &Wl[rowW][kW],     wr0, wr1);
        store_pair(&Wh[rowW][kW + 8], &Wl[rowW][kW + 8], wr2, wr3);
        __syncthreads();
        if (kt < 3) {                           // prefetch next K-tile; retires under MFMAs
            int ko = (kt + 1) * 64;
            ar0 = *(const float4*)(Asrc + ko);      ar1 = *(const float4*)(Asrc + ko + 4);
            wr0 = *(const float4*)(Wsrc + ko);      wr1 = *(const float4*)(Wsrc + ko + 4);
            wr2 = *(const float4*)(Wsrc + ko + 8);  wr3 = *(const float4*)(Wsrc + ko + 12);
        }
#pragma unroll
        for (int s = 0; s < 2; ++s) {
            int ko = s * 32 + hgrp;
            bf16x8 ah = *(const bf16x8*)&Ah[wm * 16 + r15][ko];
            bf16x8 al = *(const bf16x8*)&Al[wm * 16 + r15][ko];
            bf16x8 bh0 = *(const bf16x8*)&Wh[wn * 32 + r15][ko];
            bf16x8 bh1 = *(const bf16x8*)&Wh[wn * 32 + 16 + r15][ko];
            bf16x8 bl0 = *(const bf16x8*)&Wl[wn * 32 + r15][ko];
            bf16x8 bl1 = *(const bf16x8*)&Wl[wn * 32 + 16 + r15][ko];
            acc[0] = __builtin_amdgcn_mfma_f32_16x16x32_bf16(ah, bh0, acc[0], 0, 0, 0);
            acc[0] = __builtin_amdgcn_mfma_f32_16x16x32_bf16(ah, bl0, acc[0], 0, 0, 0);
            acc[0] = __builtin_amdgcn_mfma_f32_16x16x32_bf16(al, bh0, acc[0], 0, 0, 0);
            acc[1] = __builtin_amdgcn_mfma_f32_16x16x32_bf16(ah, bh1, acc[1], 0, 0, 0);
            acc[1] = __builtin_amdgcn_mfma_f32_16x16x32_bf16(ah, bl1, acc[1], 0, 0, 0);
            acc[1] = __builtin_amdgcn_mfma_f32_16x16x32_bf16(al, bh1, acc[1], 0, 0, 0);
        }
    }
    // epilogue: C/D layout col=lane&15, row=(lane>>4)*4+rr
#pragma unroll
    for (int nf = 0; nf < 2; ++nf) {
        int col = n0 + wn * 32 + nf * 16 + r15;
        int rowb = m0 + wm * 16 + ((lane >> 4) << 2);
        float bcol = J.bias[col];
        f32x4 a = acc[nf];
#pragma unroll
        for (int rr = 0; rr < 4; ++rr) {
            int m = rowb + rr;
            float v = a[rr] + bcol;
            if (J.pos) v += J.pos[(m & 255) * 256 + col];
            if (J.relu) v = fmaxf(v, 0.f);
            if (J.res) v += J.res[m * 256 + col];
            if (J.maskm && J.maskm[m]) v = 0.f;
            J.C[m * 256 + col] = v;
        }
    }
}

// PAIRED attn: one block handles qA=2P, qB=2P+1 in the SAME inner loops, sharing the
// K-row and V-row loads (tK/tV gathers are per-q, unshared): per k, 6 rows instead of
// 8 -> 25% L2 traffic cut. 1024 blocks, b=bid&7 keeps XCD affinity. Pair map bijective;
// each CU's 4 blocks sum to 1028 rows exactly. launch_bounds(256,4): 128-VGPR budget,
// 6-in-flight loop cannot spill. Softmax writes e=0 for invalid k so phase 3 sweeps
// both q over qB's superset range.
__global__ __launch_bounds__(256, 4) void attn_kernel(
    const float* __restrict__ Q, const float* __restrict__ Kp, const float* __restrict__ Vp,
    const float* __restrict__ qres, const int* __restrict__ tm,
    const float* __restrict__ tK, const float* __restrict__ tV,
    const float* __restrict__ g2, const float* __restrict__ b2,
    float* __restrict__ X2) {
    int bid = (int)blockIdx.x;
    int b = bid & 7;                    // XCD-aligned batch
    int i6 = bid >> 3;                  // 0..127
    int j = i6 & 31, a = i6 >> 5;
    int base = 2 * j + (a >> 1);        // 0..63
    int P = (a & 1) ? base : 127 - base;
    int qA = 2 * P, qB = 2 * P + 1;
    int tid = threadIdx.x, w = tid >> 6, lane = tid & 63;
    __shared__ float qrow[2][256];
    __shared__ int   stm[2][256];
    __shared__ float p[2][4][264];
    __shared__ float opart[2][4][256];
    __shared__ float denom[2][4];
    __shared__ float lnws[2][8];

    int rowbaseA = (b * 256 + qA) * 256;
    int rowbaseB = (b * 256 + qB) * 256;
    qrow[0][tid] = Q[rowbaseA + tid];
    qrow[1][tid] = Q[rowbaseB + tid];
    {
        int tA = tm[rowbaseA + tid];
        int tB = tm[rowbaseB + tid];
        stm[0][tid] = tA < 0 ? 0 : (tA > 512 ? 512 : tA);
        stm[1][tid] = tB < 0 ? 0 : (tB > 512 ? 512 : tB);
    }
    __syncthreads();

    // --- phase 1: scores for BOTH q over qB's range, k ≡ w (mod 4); batch-2
    {
        int h = lane >> 4;
        const float* qrA = &qrow[0][lane * 4];
        const float* qrB = &qrow[1][lane * 4];
        float qA0 = qrA[0], qA1 = qrA[1], qA2 = qrA[2], qA3 = qrA[3];
        float qB0 = qrB[0], qB1 = qrB[1], qB2 = qrB[2], qB3 = qrB[3];
        const float* Kb  = Kp + (size_t)(b << 8) * 256 + lane * 4;
        const float* tKb = tK + lane * 4;
        int nact = (qB >= w) ? ((qB - w) >> 2) + 1 : 0;
        int i = 0;
        for (; i + 2 <= nact; i += 2) {
            int k0 = w + 4 * i, k1 = k0 + 4;
            float4 kv0 = *(const float4*)(Kb + k0 * 256);
            float4 kv1 = *(const float4*)(Kb + k1 * 256);
            float4 tA0 = *(const float4*)(tKb + stm[0][k0] * 256);
            float4 tA1 = *(const float4*)(tKb + stm[0][k1] * 256);
            float4 tB0 = *(const float4*)(tKb + stm[1][k0] * 256);
            float4 tB1 = *(const float4*)(tKb + stm[1][k1] * 256);
            float sA0 = qA0 * (kv0.x + tA0.x) + qA1 * (kv0.y + tA0.y) + qA2 * (kv0.z + tA0.z) + qA3 * (kv0.w + tA0.w);
            float sA1 = qA0 * (kv1.x + tA1.x) + qA1 * (kv1.y + tA1.y) + qA2 * (kv1.z + tA1.z) + qA3 * (kv1.w + tA1.w);
            float sB0 = qB0 * (kv0.x + tB0.x) + qB1 * (kv0.y + tB0.y) + qB2 * (kv0.z + tB0.z) + qB3 * (kv0.w + tB0.w);
            float sB1 = qB0 * (kv1.x + tB1.x) + qB1 * (kv1.y + tB1.y) + qB2 * (kv1.z + tB1.z) + qB3 * (kv1.w + tB1.w);
            sA0 += __shfl_xor(sA0, 1, 64); sA1 += __shfl_xor(sA1, 1, 64);
            sB0 += __shfl_xor(sB0, 1, 64); sB1 += __shfl_xor(sB1, 1, 64);
            sA0 += __shfl_xor(sA0, 2, 64); sA1 += __shfl_xor(sA1, 2, 64);
            sB0 += __shfl_xor(sB0, 2, 64); sB1 += __shfl_xor(sB1, 2, 64);
            sA0 += __shfl_xor(sA0, 4, 64); sA1 += __shfl_xor(sA1, 4, 64);
            sB0 += __shfl_xor(sB0, 4, 64); sB1 += __shfl_xor(sB1, 4, 64);
            sA0 += __shfl_xor(sA0, 8, 64); sA1 += __shfl_xor(sA1, 8, 64);
            sB0 += __shfl_xor(sB0, 8, 64); sB1 += __shfl_xor(sB1, 8, 64);
            if ((lane & 15) == 0) {
                p[0][h][k0] = sA0 * 0.125f;
                p[0][h][k1] = sA1 * 0.125f;
                p[1][h][k0] = sB0 * 0.125f;
                p[1][h][k1] = sB1 * 0.125f;
            }
        }
        if (i < nact) {
            int k = w + 4 * i;
            float4 kv = *(const float4*)(Kb + k * 256);
            float4 tA4 = *(const float4*)(tKb + stm[0][k] * 256);
            float4 tB4 = *(const float4*)(tKb + stm[1][k] * 256);
            float sA = qA0 * (kv.x + tA4.x) + qA1 * (kv.y + tA4.y) + qA2 * (kv.z + tA4.z) + qA3 * (kv.w + tA4.w);
            float sB = qB0 * (kv.x + tB4.x) + qB1 * (kv.y + tB4.y) + qB2 * (kv.z + tB4.z) + qB3 * (kv.w + tB4.w);
            sA += __shfl_xor(sA, 1, 64); sB += __shfl_xor(sB, 1, 64);
            sA += __shfl_xor(sA, 2, 64); sB += __shfl_xor(sB, 2, 64);
            sA += __shfl_xor(sA, 4, 64); sB += __shfl_xor(sB, 4, 64);
            sA += __shfl_xor(sA, 8, 64); sB += __shfl_xor(sB, 8, 64);
            if ((lane & 15) == 0) {
                p[0][h][k] = sA * 0.125f;
                p[1][h][k] = sB * 0.125f;
            }
        }
    }
    __syncthreads();

    // --- softmax: wave w owns head w for BOTH q; invalid k -> e = 0 (enables shared phase 3)
    {
        float* phA = &p[0][w][0];
        float* phB = &p[1][w][0];
        float a0 = (lane       <= qA) ? phA[lane      ] : BIG_NEG_F;
        float a1 = (lane + 64  <= qA) ? phA[lane + 64 ] : BIG_NEG_F;
        float a2 = (lane + 128 <= qA) ? phA[lane + 128] : BIG_NEG_F;
        float a3 = (lane + 192 <= qA) ? phA[lane + 192] : BIG_NEG_F;
        float b0 = (lane       <= qB) ? phB[lane      ] : BIG_NEG_F;
        float b1 = (lane + 64  <= qB) ? phB[lane + 64 ] : BIG_NEG_F;
        float b2v = (lane + 128 <= qB) ? phB[lane + 128] : BIG_NEG_F;
        float b3 = (lane + 192 <= qB) ? phB[lane + 192] : BIG_NEG_F;
        float mxA = wave_max(fmaxf(fmaxf(a0, a1), fmaxf(a2, a3)));
        float mxB = wave_max(fmaxf(fmaxf(b0, b1), fmaxf(b2v, b3)));
        float eA0 = (lane       <= qA) ? __expf(a0 - mxA) : 0.f;
        float eA1 = (lane + 64  <= qA) ? __expf(a1 - mxA) : 0.f;
        float eA2 = (lane + 128 <= qA) ? __expf(a2 - mxA) : 0.f;
        float eA3 = (lane + 192 <= qA) ? __expf(a3 - mxA) : 0.f;
        float eB0 = (lane       <= qB) ? __expf(b0 - mxB) : 0.f;
        float eB1 = (lane + 64  <= qB) ? __expf(b1 - mxB) : 0.f;
        float eB2 = (lane + 128 <= qB) ? __expf(b2v - mxB) : 0.f;
        float eB3 = (lane + 192 <= qB) ? __expf(b3 - mxB) : 0.f;
        phA[lane] = eA0; phA[lane + 64] = eA1; phA[lane + 128] = eA2; phA[lane + 192] = eA3;
        phB[lane] = eB0; phB[lane + 64] = eB1; phB[lane + 128] = eB2; phB[lane + 192] = eB3;
        float sumA = wave_sum(eA0 + eA1 + eA2 + eA3);
        float sumB = wave_sum(eB0 + eB1 + eB2 + eB3);
        if (lane == 0) { denom[0][w] = sumA; denom[1][w] = sumB; }
    }
    __syncthreads();

    // --- phase 3: PV for BOTH q over qB's range (p_A is 0 beyond qA); batch-2
    {
        int hh = lane >> 4;
        const float* Vb  = Vp + (size_t)(b << 8) * 256 + lane * 4;
        const float* tVb = tV + lane * 4;
        const float* prA = &p[0][hh][0];
        const float* prB = &p[1][hh][0];
        float4 aA0 = {0.f, 0.f, 0.f, 0.f}, aA1 = aA0, aB0 = aA0, aB1 = aA0;
        int cnt = (qB >= w) ? ((qB - w) >> 2) + 1 : 0;
        int i = 0;
        for (; i + 2 <= cnt; i += 2) {
            int k0 = w + 4 * i, k1 = k0 + 4;
            float pA0 = prA[k0], pA1 = prA[k1], pB0 = prB[k0], pB1 = prB[k1];
            float4 v0 = *(const float4*)(Vb + k0 * 256);
            float4 v1 = *(const float4*)(Vb + k1 * 256);
            float4 uA0 = *(const float4*)(tVb + stm[0][k0] * 256);
            float4 uA1 = *(const float4*)(tVb + stm[0][k1] * 256);
            float4 uB0 = *(const float4*)(tVb + stm[1][k0] * 256);
            float4 uB1 = *(const float4*)(tVb + stm[1][k1] * 256);
            aA0.x += pA0 * (v0.x + uA0.x); aA0.y += pA0 * (v0.y + uA0.y); aA0.z += pA0 * (v0.z + uA0.z); aA0.w += pA0 * (v0.w + uA0.w);
            aA1.x += pA1 * (v1.x + uA1.x); aA1.y += pA1 * (v1.y + uA1.y); aA1.z += pA1 * (v1.z + uA1.z); aA1.w += pA1 * (v1.w + uA1.w);
            aB0.x += pB0 * (v0.x + uB0.x); aB0.y += pB0 * (v0.y + uB0.y); aB0.z += pB0 * (v0.z + uB0.z); aB0.w += pB0 * (v0.w + uB0.w);
            aB1.x += pB1 * (v1.x + uB1.x); aB1.y += pB1 * (v1.y + uB1.y); aB1.z += pB1 * (v1.z + uB1.z); aB1.w += pB1 * (v1.w + uB1.w);
        }
        if (i < cnt) {
            int k2 = w + 4 * i;
            float pA = prA[k2], pB = prB[k2];
            float4 v = *(const float4*)(Vb + k2 * 256);
            float4 uA = *(const float4*)(tVb + stm[0][k2] * 256);
            float4 uB = *(const float4*)(tVb + stm[1][k2] * 256);
            aA0.x += pA * (v.x + uA.x); aA0.y += pA * (v.y + uA.y);
            aA0.z += pA * (v.z + uA.z); aA0.w += pA * (v.w + uA.w);
            aB0.x += pB * (v.x + uB.x); aB0.y += pB * (v.y + uB.y);
            aB0.z += pB * (v.z + uB.z); aB0.w += pB * (v.w + uB.w);
        }
        float4 oA, oB;
        oA.x = aA0.x + aA1.x; oA.y = aA0.y + aA1.y; oA.z = aA0.z + aA1.z; oA.w = aA0.w + aA1.w;
        oB.x = aB0.x + aB1.x; oB.y = aB0.y + aB1.y; oB.z = aB0.z + aB1.z; oB.w = aB0.w + aB1.w;
        *(float4*)&opart[0][w][lane * 4] = oA;
        *(float4*)&opart[1][w][lane * 4] = oB;
    }
    __syncthreads();

    // --- combine + fused ln2 for both rows (parallel per thread, 2 barriers)
    {
        int d = tid, h = tid >> 6;
        float totA = opart[0][0][d] + opart[0][1][d] + opart[0][2][d] + opart[0][3][d];
        float totB = opart[1][0][d] + opart[1][1][d] + opart[1][2][d] + opart[1][3][d];
        float xvA = qres[rowbaseA + d] + totA / denom[0][h];
        float xvB = qres[rowbaseB + d] + totB / denom[1][h];
        float sA = wave_sum(xvA);
        float sB = wave_sum(xvB);
        if (lane == 0) { lnws[0][w] = sA; lnws[1][w] = sB; }
        __syncthreads();
        float meanA = (lnws[0][0] + lnws[0][1] + lnws[0][2] + lnws[0][3]) * (1.f / 256.f);
        float meanB = (lnws[1][0] + lnws[1][1] + lnws[1][2] + lnws[1][3]) * (1.f / 256.f);
        float ddA = xvA - meanA, ddB = xvB - meanB;
        float s2A = wave_sum(ddA * ddA);
        float s2B = wave_sum(ddB * ddB);
        if (lane == 0) { lnws[0][4 + w] = s2A; lnws[1][4 + w] = s2B; }
        __syncthreads();
        float varA = (lnws[0][4] + lnws[0][5] + lnws[0][6] + lnws[0][7]) * (1.f / 256.f);
        float varB = (lnws[1][4] + lnws[1][5] + lnws[1][6] + lnws[1][7]) * (1.f / 256.f);
        float gg = g2[d], bb = b2[d];
        X2[rowbaseA + d] = ddA / sqrtf(varA + 1e-8f) * gg + bb;
        X2[rowbaseB + d] = ddB / sqrtf(varB + 1e-8f) * gg + bb;
    }
}

extern "C" void kernel_launch(void* const* d_in, const int* in_sizes, int n_in,
                              void* d_out, int out_size, void* d_ws, size_t ws_size,
                              hipStream_t stream) {
    const unsigned char* mask_raw = (const unsigned char*)d_in[0];
    const float* seq  = (const float*)d_in[1];
    const int*   tm   = (const int*)d_in[3];
    const float* Wq   = (const float*)d_in[5];
    const float* bq   = (const float*)d_in[6];
    const float* Wk   = (const float*)d_in[7];
    const float* bk   = (const float*)d_in[8];
    const float* Wv   = (const float*)d_in[9];
    const float* bv   = (const float*)d_in[10];
    const float* ln1g = (const float*)d_in[11];
    const float* ln1b = (const float*)d_in[12];
    const float* ln2g = (const float*)d_in[13];
    const float* ln2b = (const float*)d_in[14];
    const float* W1   = (const float*)d_in[15];
    const float* b1   = (const float*)d_in[16];
    const float* W2   = (const float*)d_in[17];
    const float* b2   = (const float*)d_in[18];
    const float* posK = (const float*)d_in[19];
    const float* posV = (const float*)d_in[20];
    const float* tK   = (const float*)d_in[21];
    const float* tV   = (const float*)d_in[22];
    const float* lnfg = (const float*)d_in[23];
    const float* lnfb = (const float*)d_in[24];

    const int NEL = 8 * 256 * 256;
    float* x   = (float*)d_ws;
    float* q   = x   + NEL;
    float* Qb  = q   + NEL;
    float* KpB = Qb  + NEL;
    float* VpB = KpB + NEL;
    float* x2  = VpB + NEL;
    float* hb  = x2  + NEL;
    unsigned char* mask = (unsigned char*)(hb + NEL);

    dim3 gQKV(4, 64, 3);   // 32x64 tiles: 768 blocks = 3/CU
    dim3 gFFN(4, 64, 1);   // 256 blocks = 1/CU

    prep_ln_kernel<<<2048, 256, 0, stream>>>(seq, mask_raw, mask, x, q, ln1g, ln1b);
    for (int blk = 0; blk < 2; ++blk) {
        int o1 = blk * 256, oW = blk * 256 * 256;
        GemmJob jq = {q, Wq + oW, bq + o1, nullptr, nullptr, nullptr, Qb, 0};
        GemmJob jk = {x, Wk + oW, bk + o1, posK,    nullptr, nullptr, KpB, 0};
        GemmJob jv = {x, Wv + oW, bv + o1, posV,    nullptr, nullptr, VpB, 0};
        gemm_mfma_kernel<<<gQKV, 256, 0, stream>>>(jq, jk, jv);
        attn_kernel<<<1024, 256, 0, stream>>>(Qb, KpB, VpB, q, tm, tK, tV,
                                              ln2g + o1, ln2b + o1, x2);
        GemmJob f1 = {x2, W1 + oW, b1 + o1, nullptr, nullptr, nullptr, hb, 1};
        gemm_mfma_kernel<<<gFFN, 256, 0, stream>>>(f1, f1, f1);
        GemmJob f2 = {hb, W2 + oW, b2 + o1, nullptr, x2, mask, x, 0};
        gemm_mfma_kernel<<<gFFN, 256, 0, stream>>>(f2, f2, f2);
        if (blk == 0) ln_kernel<<<2048, 256, 0, stream>>>(x, q, ln1g + 256, ln1b + 256);
    }
    ln_kernel<<<2048, 256, 0, stream>>>(x, (float*)d_out, lnfg, lnfb);
}